// Round 6
// baseline (235.741 us; speedup 1.0000x reference)
//
#include <hip/hip_runtime.h>

#define DEV __device__ __forceinline__

typedef __attribute__((ext_vector_type(8))) short bf16x8;
typedef __attribute__((ext_vector_type(4))) float f32x4;

#define MFMA(a, b, c) __builtin_amdgcn_mfma_f32_16x16x32_bf16(a, b, c, 0, 0, 0)

// sizes (fixed problem)
#define BS 2
#define S 2048
#define DM 768
#define NH 8
#define DK 64
#define NPROJ 512   // NH*DK
#define BH 16       // BS*NH
#define KC 32       // S/64
#define CTXP_SLICE 2097152  // 256*16*512 shorts per split-slice

DEV unsigned short f2bf(float f) {
    unsigned int u = __float_as_uint(f);
    unsigned int r = u + 0x7fffu + ((u >> 16) & 1u);
    return (unsigned short)(r >> 16);
}

DEV float redsum16(float v) {
    v += __shfl_xor(v, 1);
    v += __shfl_xor(v, 2);
    v += __shfl_xor(v, 4);
    v += __shfl_xor(v, 8);
    return v;
}

// ---------- fused prep: acast (blk<9216) | mask bits (<9728) | wfrag (<10880) ----------
__global__ __launch_bounds__(256) void k_prep(
    const float* __restrict__ q, const float* __restrict__ k, const float* __restrict__ v,
    const unsigned char* __restrict__ mask,
    const float* __restrict__ Wq, const float* __restrict__ Wk, const float* __restrict__ Wv,
    const float* __restrict__ Wo,
    unsigned short* __restrict__ Af, unsigned long long* __restrict__ bits,
    unsigned short* __restrict__ Oq, unsigned short* __restrict__ Ok,
    unsigned short* __restrict__ Ov, unsigned short* __restrict__ Oo) {
    int blk = blockIdx.x;
    if (blk < 9216) {
        // q,k,v fp32 -> bf16 MFMA-A-fragment order
        int p = blk / 3072;
        int f = (blk % 3072) * 256 + threadIdx.x;
        const float* A = (p == 0) ? q : ((p == 1) ? k : v);
        float4 x = *(const float4*)(A + (size_t)f * 4);
        int col4 = f % 192, row = f / 192;
        int c0 = col4 * 4;
        int ks = c0 >> 5, lgp = (c0 & 31) >> 3, e0 = c0 & 7;
        int rt = p * 256 + (row >> 4);
        size_t dst = ((size_t)(rt * 24 + ks) * 64 + lgp * 16 + (row & 15)) * 8 + e0;
        ushort4 o;
        o.x = f2bf(x.x); o.y = f2bf(x.y); o.z = f2bf(x.z); o.w = f2bf(x.w);
        *(ushort4*)(Af + dst) = o;
    } else if (blk < 9728) {
        // mask bytes -> bitmask
        int w = (blk - 9216) * 256 + threadIdx.x;
        const unsigned long long* m8 = (const unsigned long long*)(mask + (size_t)w * 64);
        unsigned long long out = 0ull;
#pragma unroll
        for (int i = 0; i < 8; i++) {
            unsigned long long xv = m8[i];
#pragma unroll
            for (int kk = 0; kk < 8; kk++)
                if ((xv >> (8 * kk)) & 0xffull) out |= 1ull << (i * 8 + kk);
        }
        bits[w] = out;
    } else {
        // W -> MFMA-B-fragment order
        int i = blk - 9728;                  // 0..1151
        int ks = i % 24, byy = (i / 24) % 12, z = i / 288;
        const float* W = (z == 0) ? Wq : ((z == 1) ? Wk : ((z == 2) ? Wv : Wo));
        unsigned short* out = (z == 0) ? Oq : ((z == 1) ? Ok : ((z == 2) ? Ov : Oo));
        int N = (z == 3) ? DM : NPROJ;
        float scale = (z == 0) ? 0.125f : 1.0f;
        int wave = threadIdx.x >> 6, lane = threadIdx.x & 63;
        int nc = byy * 4 + wave;
        if (z < 3) { if (ks >= 24 || nc >= 32) return; }
        else       { if (ks >= 16) return; }
        int lr = lane & 15, lg = lane >> 4;
        int NC = N >> 4;
        const float* src = W + (size_t)(ks * 32 + lg * 8) * N + nc * 16 + lr;
        bf16x8 vv;
#pragma unroll
        for (int e = 0; e < 8; e++) vv[e] = (short)f2bf(src[(size_t)e * N] * scale);
        *(bf16x8*)(out + ((size_t)(ks * NC + nc) * 64 + lane) * 8) = vv;
    }
}

// ---------- projection GEMM: Af(frag) x Wfrag -> Qh/Kf/Vf via LDS repack + coalesced flush ----------
__global__ __launch_bounds__(256, 3) void k_proj(
    const unsigned short* __restrict__ Af,
    const unsigned short* __restrict__ Wfq, const unsigned short* __restrict__ Wfk,
    const unsigned short* __restrict__ Wfv,
    unsigned short* __restrict__ Qh, unsigned short* __restrict__ Kf,
    unsigned short* __restrict__ Vf) {
    __shared__ __align__(16) unsigned short ls[4096];  // 8 KB repack buffer
    // XCD-aware decode: all 4 by-blocks of one (p,bx) land on the same XCD
    int lin = blockIdx.x;                    // 0..767
    int x = lin & 7, r = lin >> 3;           // r 0..95
    int by = r & 3;
    int pbx = (r >> 2) * 8 + x;              // 0..191
    int p = pbx >> 6, bx = pbx & 63;

    const unsigned short* wf = (p == 0) ? Wfq : ((p == 1) ? Wfk : Wfv);

    const int wave = threadIdx.x >> 6, lane = threadIdx.x & 63;
    const int lr = lane & 15, lg = lane >> 4;

    f32x4 zero = {0.f, 0.f, 0.f, 0.f};
    f32x4 acc[8] = {zero, zero, zero, zero, zero, zero, zero, zero};

    const unsigned short* afb =
        Af + ((size_t)(p * 256 + bx * 4 + wave) * 24) * 512 + (size_t)lane * 8;
    bf16x8 a = *(const bf16x8*)afb;
#pragma unroll
    for (int ks = 0; ks < 24; ks++) {
        bf16x8 an;
        if (ks < 23) an = *(const bf16x8*)(afb + (ks + 1) * 512);
        const unsigned short* wp = wf + ((size_t)(ks * 32 + by * 8) * 64 + lane) * 8;
#pragma unroll
        for (int nt = 0; nt < 8; nt++) {
            bf16x8 b = *(const bf16x8*)(wp + (size_t)nt * 512);
            acc[nt] = MFMA(a, b, acc[nt]);
        }
        a = an;
    }

    const int bb = bx >> 5, kq = bx & 31;  // batch, kc (or 64-row group for Q)
#pragma unroll
    for (int half = 0; half < 2; half++) {
        if (half) __syncthreads();   // previous flush reads done before overwrite
        int h = by * 2 + half;
        int bh = bb * NH + h;
        // ---- write phase: acc -> LDS in exact global-chunk layout ----
#pragma unroll
        for (int nt4 = 0; nt4 < 4; nt4++) {
            int nt = half * 4 + nt4;
#pragma unroll
            for (int j = 0; j < 4; j++) {
                unsigned short val = f2bf(acc[nt][j]);
                int lsaddr;
                if (p == 0) {
                    lsaddr = (wave * 16 + lg * 4 + j) * 64 + nt4 * 16 + lr;
                } else if (p == 1) {
                    int hh = nt4 >> 1;
                    int lgk = ((nt4 & 1) << 1) | (lr >> 3);
                    lsaddr = (wave * 2 + hh) * 512 + (lgk * 16 + lg * 4 + j) * 8 + (lr & 7);
                } else {
                    int hh = wave >> 1;
                    int lgv = ((wave & 1) << 1) | (lg >> 1);
                    lsaddr = (nt4 * 2 + hh) * 512 + (lgv * 16 + lr) * 8 + (lg & 1) * 4 + j;
                }
                ls[lsaddr] = val;
            }
        }
        __syncthreads();
        // ---- flush: 8 KB coalesced ----
        unsigned short* gp;
        if (p == 0)      gp = Qh + ((size_t)bh * S + kq * 64) * DK;
        else if (p == 1) gp = Kf + ((size_t)bh * KC + kq) * 4096;
        else             gp = Vf + ((size_t)bh * KC + kq) * 4096;
        const uint4* lsv = (const uint4*)ls;
        uint4 v0 = lsv[threadIdx.x * 2];
        uint4 v1 = lsv[threadIdx.x * 2 + 1];
        *(uint4*)(gp + threadIdx.x * 16) = v0;
        *(uint4*)(gp + threadIdx.x * 16 + 8) = v1;
    }
}

// ---------- softmax denominators, K-split for occupancy ----------
__global__ __launch_bounds__(256, 4) void k_lsum(
    const unsigned short* __restrict__ Qh, const unsigned short* __restrict__ Kf,
    const unsigned long long* __restrict__ mbits, float* __restrict__ lpart) {
    int lin = blockIdx.x;
    int x = lin & 7, i = lin >> 3;          // i 0..255
    int bh = (x << 1) | (i >> 7);
    int i7 = i & 127;
    int qc = i7 >> 2, ks = i7 & 3;
    int b = bh >> 3;
    const int wave = threadIdx.x >> 6, lane = threadIdx.x & 63;
    const int lr = lane & 15, lg = lane >> 4;
    const int qbase = qc * 64 + wave * 16;

    const unsigned short* qp = Qh + ((size_t)bh * S + qbase + lr) * DK + lg * 8;
    bf16x8 a0 = *(const bf16x8*)qp;
    bf16x8 a1 = *(const bf16x8*)(qp + 32);

    const unsigned short* kb = Kf + (size_t)bh * KC * 4096;
    const unsigned long long* mrow = mbits + (size_t)b * S * KC;

    int qr[4];
#pragma unroll
    for (int j = 0; j < 4; j++) qr[j] = qbase + lg * 4 + j;

    float lsum[4] = {0.f, 0.f, 0.f, 0.f};
    for (int kk = 0; kk < 8; kk++) {
        int kc = ks * 8 + kk;
        bf16x8 kf[8];
        unsigned long long wb[4];
#pragma unroll
        for (int u = 0; u < 8; u++)
            kf[u] = *(const bf16x8*)(kb + ((size_t)kc * 8 + u) * 512 + lane * 8);
#pragma unroll
        for (int j = 0; j < 4; j++) wb[j] = mrow[(size_t)qr[j] * KC + kc];
        f32x4 s[4];
#pragma unroll
        for (int t = 0; t < 4; t++) {
            f32x4 z = {0.f, 0.f, 0.f, 0.f};
            z = MFMA(a0, kf[t * 2], z);
            z = MFMA(a1, kf[t * 2 + 1], z);
            s[t] = z;
        }
#pragma unroll
        for (int t = 0; t < 4; t++)
#pragma unroll
            for (int j = 0; j < 4; j++) {
                float sv = ((wb[j] >> (t * 16 + lr)) & 1ull) ? -1e9f : s[t][j];
                lsum[j] += __expf(sv);
            }
    }
#pragma unroll
    for (int j = 0; j < 4; j++) {
        float tot = redsum16(lsum[j]);
        if (lr == 0) lpart[((size_t)bh * S + qr[j]) * 4 + ks] = tot;
    }
}

// ---------- attention, kc-split x2: scores -> weights + partial PV -> ctxP slice ----------
__global__ __launch_bounds__(256, 3) void k_attn(
    const unsigned short* __restrict__ Qh, const unsigned short* __restrict__ Kf,
    const unsigned short* __restrict__ Vf, const unsigned long long* __restrict__ mbits,
    const float* __restrict__ lpart, float* __restrict__ wout,
    unsigned short* __restrict__ ctxP) {
    __shared__ __align__(16) char smem[4 * 6400];  // per wave: fp32 tile [16][68] + bf16 P tile
    int lin = blockIdx.x;                 // 0..1023
    int x = lin & 7, i = lin >> 3;        // i 0..127
    int bh = (x << 1) | (i >> 6);
    int rem = i & 63;
    int qc = rem >> 1, ks2 = rem & 1;
    int b = bh >> 3, h = bh & 7;
    const int wave = threadIdx.x >> 6, lane = threadIdx.x & 63;
    const int lr = lane & 15, lg = lane >> 4;
    const int qbase = qc * 64 + wave * 16;

    const unsigned short* qp = Qh + ((size_t)bh * S + qbase + lr) * DK + lg * 8;
    bf16x8 a0 = *(const bf16x8*)qp;
    bf16x8 a1 = *(const bf16x8*)(qp + 32);

    const unsigned short* kb = Kf + (size_t)bh * KC * 4096;
    const unsigned short* vb = Vf + (size_t)bh * KC * 4096;
    const unsigned long long* mrow = mbits + (size_t)b * S * KC;

    int qr[4];
#pragma unroll
    for (int j = 0; j < 4; j++) qr[j] = qbase + lg * 4 + j;

    float linv[4];
#pragma unroll
    for (int j = 0; j < 4; j++) {
        f32x4 lp = *(const f32x4*)(lpart + ((size_t)bh * S + qr[j]) * 4);
        linv[j] = 1.f / (lp[0] + lp[1] + lp[2] + lp[3]);
    }

    f32x4 zero = {0.f, 0.f, 0.f, 0.f};
    f32x4 c[4] = {zero, zero, zero, zero};
    char* wbase = smem + wave * 6400;
    float* tile = (float*)wbase;        // [16][68] fp32 (16B-aligned rows)
    char* wt = wbase + 4352;            // 16x64 bf16, XOR-swizzled
    float* wo = wout + (size_t)bh * S * S;

    const int kc0 = ks2 * 16;
    for (int kk = 0; kk < 16; kk++) {
        int kc = kc0 + kk;
        unsigned long long wb[4];
#pragma unroll
        for (int j = 0; j < 4; j++) wb[j] = mrow[(size_t)qr[j] * KC + kc];
        bf16x8 kf[8], vf[8];
#pragma unroll
        for (int u = 0; u < 8; u++)
            kf[u] = *(const bf16x8*)(kb + ((size_t)kc * 8 + u) * 512 + lane * 8);
#pragma unroll
        for (int u = 0; u < 8; u++)
            vf[u] = *(const bf16x8*)(vb + ((size_t)kc * 8 + u) * 512 + lane * 8);

        f32x4 s[4];
        __builtin_amdgcn_s_setprio(1);
#pragma unroll
        for (int t = 0; t < 4; t++) {
            f32x4 z = {0.f, 0.f, 0.f, 0.f};
            z = MFMA(a0, kf[t * 2], z);
            z = MFMA(a1, kf[t * 2 + 1], z);
            s[t] = z;
        }
        __builtin_amdgcn_s_setprio(0);

        // normalized weights into both tiles
#pragma unroll
        for (int t = 0; t < 4; t++) {
#pragma unroll
            for (int j = 0; j < 4; j++) {
                float sv = ((wb[j] >> (t * 16 + lr)) & 1ull) ? -1e9f : s[t][j];
                float w = __expf(sv) * linv[j];
                int row = lg * 4 + j;
                tile[row * 68 + t * 16 + lr] = w;
                int boff = ((t * 16 + lr) * 2) ^ ((row & 7) << 4);
                *(unsigned short*)(wt + row * 128 + boff) = f2bf(w);
            }
        }
        // P tile as A-fragments (same-wave LDS roundtrip, swizzled read)
        bf16x8 pa0 = *(const bf16x8*)(wt + lr * 128 + ((lg * 16) ^ ((lr & 7) << 4)));
        bf16x8 pa1 = *(const bf16x8*)(wt + lr * 128 + ((64 + lg * 16) ^ ((lr & 7) << 4)));
        __builtin_amdgcn_s_setprio(1);
#pragma unroll
        for (int dt = 0; dt < 4; dt++) {
            c[dt] = MFMA(pa0, vf[dt * 2], c[dt]);
            c[dt] = MFMA(pa1, vf[dt * 2 + 1], c[dt]);
        }
        __builtin_amdgcn_s_setprio(0);
        // transposed readback, coalesced float4 weight stores
#pragma unroll
        for (int ii = 0; ii < 4; ii++) {
            float4 v4 = *(const float4*)(tile + lr * 68 + lg * 16 + ii * 4);
            *(float4*)(wo + (size_t)(qbase + lr) * S + kc * 64 + lg * 16 + ii * 4) = v4;
        }
    }

    // ---- partial ctx -> wave-local LDS in ctxP chunk layout, coalesced flush ----
    unsigned short* cls = (unsigned short*)wt;  // 2 KB, wave-private
#pragma unroll
    for (int dt = 0; dt < 4; dt++)
#pragma unroll
        for (int j = 0; j < 4; j++)
            cls[(dt >> 1) * 512 + (((dt & 1) * 2 + (lr >> 3)) * 16 + lg * 4 + j) * 8 + (lr & 7)] =
                f2bf(c[dt][j]);
    int rtc = b * 128 + qc * 4 + wave;
    unsigned short* gp = ctxP + (size_t)ks2 * CTXP_SLICE +
                         ((size_t)(rtc * 16 + h * 2)) * 512 + lane * 16;
    const uint4* clsv = (const uint4*)cls;
    uint4 u0 = clsv[lane * 2];
    uint4 u1 = clsv[lane * 2 + 1];
    *(uint4*)gp = u0;
    *(uint4*)(gp + 8) = u1;
}

// ---------- output projection: (ctxP[0] + ctxP[1]) x Wofrag via 32-step MFMA accumulation ----------
__global__ __launch_bounds__(256, 3) void k_outproj(const unsigned short* __restrict__ ctxP,
                                                    const unsigned short* __restrict__ wfo,
                                                    float* __restrict__ out) {
    int lin = blockIdx.x;                 // 0..767
    int x = lin & 7, r = lin >> 3;        // r 0..95
    int by = r >> 3, bxg = r & 7;         // by 0..11
    int bx = bxg * 8 + x;

    const int wave = threadIdx.x >> 6, lane = threadIdx.x & 63;
    const int lr = lane & 15, lg = lane >> 4;

    f32x4 zero = {0.f, 0.f, 0.f, 0.f};
    f32x4 acc[4] = {zero, zero, zero, zero};

#pragma unroll
    for (int sl = 0; sl < 2; sl++) {
        const unsigned short* ap = ctxP + (size_t)sl * CTXP_SLICE +
                                   ((size_t)(bx * 4 + wave) * 16) * 512 + (size_t)lane * 8;
        bf16x8 a = *(const bf16x8*)ap;
#pragma unroll
        for (int ks = 0; ks < 16; ks++) {
            bf16x8 an;
            if (ks < 15) an = *(const bf16x8*)(ap + (ks + 1) * 512);
#pragma unroll
            for (int nt = 0; nt < 4; nt++) {
                const unsigned short* bp = wfo + ((size_t)(ks * 48 + by * 4 + nt) * 64 + lane) * 8;
                bf16x8 bb = *(const bf16x8*)bp;
                acc[nt] = MFMA(a, bb, acc[nt]);
            }
            a = an;
        }
    }
#pragma unroll
    for (int nt = 0; nt < 4; nt++) {
        int col = by * 64 + nt * 16 + lr;
#pragma unroll
        for (int j = 0; j < 4; j++) {
            int rr = bx * 64 + wave * 16 + lg * 4 + j;
            out[(size_t)rr * DM + col] = acc[nt][j];
        }
    }
}

extern "C" void kernel_launch(void* const* d_in, const int* in_sizes, int n_in,
                              void* d_out, int out_size, void* d_ws, size_t ws_size,
                              hipStream_t stream) {
    const float* q = (const float*)d_in[0];
    const float* k = (const float*)d_in[1];
    const float* v = (const float*)d_in[2];
    const unsigned char* mask = (const unsigned char*)d_in[3];
    const float* Wq = (const float*)d_in[4];
    const float* Wk = (const float*)d_in[5];
    const float* Wv = (const float*)d_in[6];
    const float* Wo = (const float*)d_in[7];

    float* out = (float*)d_out;
    float* weights = out + (size_t)BS * S * DM;
    // Af (18.9 MB) lives at the start of the weights region (dead once k_proj ends;
    // k_attn overwrites it with real weights afterwards).
    unsigned short* Af = (unsigned short*)weights;
    // mbits (1 MB) + lpart (0.5 MB) live in the `out` region: written by k_prep/k_lsum,
    // last read by k_attn, clobbered only by k_outproj's final stores.
    unsigned long long* mbits = (unsigned long long*)out;
    float* lpart = (float*)((char*)out + 1048576);

    char* ws = (char*)d_ws;
    const size_t WT_SZ = (size_t)393216 * 2;         // 768 KiB each
    const size_t HEAD_SZ = (size_t)BH * S * DK * 2;  // 4 MiB
    unsigned short* Wfq = (unsigned short*)(ws + 0 * WT_SZ);
    unsigned short* Wfk = (unsigned short*)(ws + 1 * WT_SZ);
    unsigned short* Wfv = (unsigned short*)(ws + 2 * WT_SZ);
    unsigned short* Wfo = (unsigned short*)(ws + 3 * WT_SZ);
    char* base = ws + 4 * WT_SZ;
    unsigned short* Qh = (unsigned short*)(base + 0 * HEAD_SZ);
    unsigned short* Kf = (unsigned short*)(base + 1 * HEAD_SZ);
    unsigned short* Vf = (unsigned short*)(base + 2 * HEAD_SZ);
    unsigned short* ctxP = (unsigned short*)(base + 3 * HEAD_SZ);  // 2 slices = 8.39 MB
    if (ws_size < 4 * WT_SZ + 3 * HEAD_SZ + 2 * (size_t)CTXP_SLICE * 2) return;  // 23 MiB

    k_prep<<<10880, 256, 0, stream>>>(q, k, v, mask, Wq, Wk, Wv, Wo, Af, mbits,
                                      Wfq, Wfk, Wfv, Wfo);
    k_proj<<<768, 256, 0, stream>>>(Af, Wfq, Wfk, Wfv, Qh, Kf, Vf);
    k_lsum<<<2048, 256, 0, stream>>>(Qh, Kf, mbits, lpart);
    k_attn<<<1024, 256, 0, stream>>>(Qh, Kf, Vf, mbits, lpart, weights, ctxP);
    k_outproj<<<768, 256, 0, stream>>>(ctxP, Wfo, out);
}

// Round 8
// 174.642 us; speedup vs baseline: 1.3499x; 1.3499x over previous
//
#include <hip/hip_runtime.h>
#include <hip/hip_bf16.h>

#define DEV __device__ __forceinline__

typedef __attribute__((ext_vector_type(8))) short bf16x8;
typedef __attribute__((ext_vector_type(4))) float f32x4;

#define MFMA(a, b, c) __builtin_amdgcn_mfma_f32_16x16x32_bf16(a, b, c, 0, 0, 0)

// sizes (fixed problem)
#define BS 2
#define S 2048
#define DM 768
#define NH 8
#define DK 64
#define NPROJ 512   // NH*DK
#define BH 16       // BS*NH
#define KC 32       // S/64
#define LOG2E 1.44269504089f

DEV unsigned short f2bf(float f) {
    unsigned int u = __float_as_uint(f);
    unsigned int r = u + 0x7fffu + ((u >> 16) & 1u);
    return (unsigned short)(r >> 16);
}

// ---------- fused prep: acast (blk<9216) | mask bits (<9728) | wfrag (<10880) ----------
__global__ __launch_bounds__(256) void k_prep(
    const float* __restrict__ q, const float* __restrict__ k, const float* __restrict__ v,
    const unsigned char* __restrict__ mask,
    const float* __restrict__ Wq, const float* __restrict__ Wk, const float* __restrict__ Wv,
    const float* __restrict__ Wo,
    unsigned short* __restrict__ Af, unsigned long long* __restrict__ bits,
    unsigned short* __restrict__ Oq, unsigned short* __restrict__ Ok,
    unsigned short* __restrict__ Ov, unsigned short* __restrict__ Oo) {
    int blk = blockIdx.x;
    if (blk < 9216) {
        // q,k,v fp32 -> bf16 MFMA-A-fragment order
        int p = blk / 3072;
        int f = (blk % 3072) * 256 + threadIdx.x;
        const float* A = (p == 0) ? q : ((p == 1) ? k : v);
        float4 x = *(const float4*)(A + (size_t)f * 4);
        int col4 = f % 192, row = f / 192;
        int c0 = col4 * 4;
        int ks = c0 >> 5, lgp = (c0 & 31) >> 3, e0 = c0 & 7;
        int rt = p * 256 + (row >> 4);
        size_t dst = ((size_t)(rt * 24 + ks) * 64 + lgp * 16 + (row & 15)) * 8 + e0;
        ushort4 o;
        o.x = f2bf(x.x); o.y = f2bf(x.y); o.z = f2bf(x.z); o.w = f2bf(x.w);
        *(ushort4*)(Af + dst) = o;
    } else if (blk < 9728) {
        // mask bytes -> bitmask
        int w = (blk - 9216) * 256 + threadIdx.x;
        const unsigned long long* m8 = (const unsigned long long*)(mask + (size_t)w * 64);
        unsigned long long out = 0ull;
#pragma unroll
        for (int i = 0; i < 8; i++) {
            unsigned long long xv = m8[i];
#pragma unroll
            for (int kk = 0; kk < 8; kk++)
                if ((xv >> (8 * kk)) & 0xffull) out |= 1ull << (i * 8 + kk);
        }
        bits[w] = out;
    } else {
        // W -> MFMA-B-fragment order
        int i = blk - 9728;                  // 0..1151
        int ks = i % 24, byy = (i / 24) % 12, z = i / 288;
        const float* W = (z == 0) ? Wq : ((z == 1) ? Wk : ((z == 2) ? Wv : Wo));
        unsigned short* out = (z == 0) ? Oq : ((z == 1) ? Ok : ((z == 2) ? Ov : Oo));
        int N = (z == 3) ? DM : NPROJ;
        float scale = (z == 0) ? 0.125f : 1.0f;
        int wave = threadIdx.x >> 6, lane = threadIdx.x & 63;
        int nc = byy * 4 + wave;
        if (z < 3) { if (ks >= 24 || nc >= 32) return; }
        else       { if (ks >= 16) return; }
        int lr = lane & 15, lg = lane >> 4;
        int NC = N >> 4;
        const float* src = W + (size_t)(ks * 32 + lg * 8) * N + nc * 16 + lr;
        bf16x8 vv;
#pragma unroll
        for (int e = 0; e < 8; e++) vv[e] = (short)f2bf(src[(size_t)e * N] * scale);
        *(bf16x8*)(out + ((size_t)(ks * NC + nc) * 64 + lane) * 8) = vv;
    }
}

// ---------- projection GEMM: Af(frag) x Wfrag -> Qh/Kf/Vf via LDS repack + coalesced flush ----------
// Vf key-rows are stored pre-permuted by pi(h*32+lg*8+e) = h*32+(e>>2)*16+lg*4+(e&3)
// so k_attn's P fragments need no cross-lane movement.
__global__ __launch_bounds__(256, 3) void k_proj(
    const unsigned short* __restrict__ Af,
    const unsigned short* __restrict__ Wfq, const unsigned short* __restrict__ Wfk,
    const unsigned short* __restrict__ Wfv,
    unsigned short* __restrict__ Qh, unsigned short* __restrict__ Kf,
    unsigned short* __restrict__ Vf) {
    __shared__ __align__(16) unsigned short ls[4096];  // 8 KB repack buffer
    // XCD-aware decode: all 4 by-blocks of one (p,bx) land on the same XCD
    int lin = blockIdx.x;                    // 0..767
    int x = lin & 7, r = lin >> 3;           // r 0..95
    int by = r & 3;
    int pbx = (r >> 2) * 8 + x;              // 0..191
    int p = pbx >> 6, bx = pbx & 63;

    const unsigned short* wf = (p == 0) ? Wfq : ((p == 1) ? Wfk : Wfv);

    const int wave = threadIdx.x >> 6, lane = threadIdx.x & 63;
    const int lr = lane & 15, lg = lane >> 4;

    f32x4 zero = {0.f, 0.f, 0.f, 0.f};
    f32x4 acc[8] = {zero, zero, zero, zero, zero, zero, zero, zero};

    const unsigned short* afb =
        Af + ((size_t)(p * 256 + bx * 4 + wave) * 24) * 512 + (size_t)lane * 8;
    bf16x8 a = *(const bf16x8*)afb;
#pragma unroll
    for (int ks = 0; ks < 24; ks++) {
        bf16x8 an;
        if (ks < 23) an = *(const bf16x8*)(afb + (ks + 1) * 512);
        const unsigned short* wp = wf + ((size_t)(ks * 32 + by * 8) * 64 + lane) * 8;
#pragma unroll
        for (int nt = 0; nt < 8; nt++) {
            bf16x8 b = *(const bf16x8*)(wp + (size_t)nt * 512);
            acc[nt] = MFMA(a, b, acc[nt]);
        }
        a = an;
    }

    const int bb = bx >> 5, kq = bx & 31;  // batch, kc (or 64-row group for Q)
#pragma unroll
    for (int half = 0; half < 2; half++) {
        if (half) __syncthreads();   // previous flush reads done before overwrite
        int h = by * 2 + half;
        int bh = bb * NH + h;
        // ---- write phase: acc -> LDS in exact global-chunk layout ----
#pragma unroll
        for (int nt4 = 0; nt4 < 4; nt4++) {
            int nt = half * 4 + nt4;
#pragma unroll
            for (int j = 0; j < 4; j++) {
                unsigned short val = f2bf(acc[nt][j]);
                int lsaddr;
                if (p == 0) {
                    lsaddr = (wave * 16 + lg * 4 + j) * 64 + nt4 * 16 + lr;
                } else if (p == 1) {
                    int hh = nt4 >> 1;
                    int lgk = ((nt4 & 1) << 1) | (lr >> 3);
                    lsaddr = (wave * 2 + hh) * 512 + (lgk * 16 + lg * 4 + j) * 8 + (lr & 7);
                } else {
                    // V with pi-permuted key rows: klo = wave*16+lg*4+j
                    // hh=klo>>5=wave>>1; lg_frag=(klo&15)>>2=lg; e=((klo>>4)&1)*4+(klo&3)=(wave&1)*4+j
                    lsaddr = (nt4 * 2 + (wave >> 1)) * 512 + (lg * 16 + lr) * 8 + (wave & 1) * 4 + j;
                }
                ls[lsaddr] = val;
            }
        }
        __syncthreads();
        // ---- flush: 8 KB coalesced ----
        unsigned short* gp;
        if (p == 0)      gp = Qh + ((size_t)bh * S + kq * 64) * DK;
        else if (p == 1) gp = Kf + ((size_t)bh * KC + kq) * 4096;
        else             gp = Vf + ((size_t)bh * KC + kq) * 4096;
        const uint4* lsv = (const uint4*)ls;
        uint4 v0 = lsv[threadIdx.x * 2];
        uint4 v1 = lsv[threadIdx.x * 2 + 1];
        *(uint4*)(gp + threadIdx.x * 16) = v0;
        *(uint4*)(gp + threadIdx.x * 16 + 8) = v1;
    }
}

// ---------- softmax denominators (swapped QK^T: lane-local rows), K-split x4 ----------
__global__ __launch_bounds__(256, 4) void k_lsum(
    const unsigned short* __restrict__ Qh, const unsigned short* __restrict__ Kf,
    const unsigned long long* __restrict__ mbits, float* __restrict__ lpart) {
    int lin = blockIdx.x;
    int x = lin & 7, i = lin >> 3;          // i 0..255
    int bh = (x << 1) | (i >> 7);
    int i7 = i & 127;
    int qc = i7 >> 2, ks = i7 & 3;
    int b = bh >> 3;
    const int wave = threadIdx.x >> 6, lane = threadIdx.x & 63;
    const int lr = lane & 15, lg = lane >> 4;
    const int qbase = qc * 64 + wave * 16;
    const int myrow = qbase + lr;

    const unsigned short* qp = Qh + ((size_t)bh * S + myrow) * DK + lg * 8;
    bf16x8 a0 = *(const bf16x8*)qp;
    bf16x8 a1 = *(const bf16x8*)(qp + 32);

    const unsigned short* kb = Kf + (size_t)bh * KC * 4096;
    const unsigned long long* mrow = mbits + (size_t)b * S * KC + (size_t)myrow * KC;

    float lsum = 0.f;
    for (int kk = 0; kk < 8; kk++) {
        int kc = ks * 8 + kk;
        unsigned long long wb = mrow[kc];
        bf16x8 kf[8];
#pragma unroll
        for (int u = 0; u < 8; u++)
            kf[u] = *(const bf16x8*)(kb + ((size_t)kc * 8 + u) * 512 + lane * 8);
        f32x4 s[4];
#pragma unroll
        for (int t = 0; t < 4; t++) {
            f32x4 z = {0.f, 0.f, 0.f, 0.f};
            z = MFMA(kf[t * 2], a0, z);       // swapped: rows=keys, cols=q
            z = MFMA(kf[t * 2 + 1], a1, z);
            s[t] = z;
        }
#pragma unroll
        for (int t = 0; t < 4; t++)
#pragma unroll
            for (int j = 0; j < 4; j++) {
                float p = exp2f(s[t][j] * LOG2E);
                if ((wb >> (t * 16 + lg * 4 + j)) & 1ull) p = 0.f;
                lsum += p;
            }
    }
    lsum += __shfl_xor(lsum, 16);
    lsum += __shfl_xor(lsum, 32);
    if (lg == 0) lpart[((size_t)bh * S + myrow) * 4 + ks] = lsum;
}

// ---------- single-pass attention, swapped scores: weights direct-store + shuffle-free PV ----------
__global__ __launch_bounds__(256, 2) void k_attn(
    const unsigned short* __restrict__ Qh, const unsigned short* __restrict__ Kf,
    const unsigned short* __restrict__ Vf, const unsigned long long* __restrict__ mbits,
    const float* __restrict__ lpart, float* __restrict__ wout,
    unsigned short* __restrict__ ctxF) {
    __shared__ __align__(16) char smem[4 * 2048];  // per-wave ctx repack only
    int lin = blockIdx.x;                 // 0..511
    int x = lin & 7, i = lin >> 3;        // i 0..63
    int bh = (x << 1) | (i >> 5), qc = i & 31;
    int b = bh >> 3, h = bh & 7;
    const int wave = threadIdx.x >> 6, lane = threadIdx.x & 63;
    const int lr = lane & 15, lg = lane >> 4;
    const int qbase = qc * 64 + wave * 16;
    const int myrow = qbase + lr;

    const unsigned short* qp = Qh + ((size_t)bh * S + myrow) * DK + lg * 8;
    bf16x8 a0 = *(const bf16x8*)qp;
    bf16x8 a1 = *(const bf16x8*)(qp + 32);

    const unsigned short* kb = Kf + (size_t)bh * KC * 4096;
    const unsigned short* vb = Vf + (size_t)bh * KC * 4096;
    const unsigned long long* mrow = mbits + (size_t)b * S * KC + (size_t)myrow * KC;

    // fold 1/l into the exponent: w = exp2(s*log2e - log2(l))
    f32x4 lp = *(const f32x4*)(lpart + ((size_t)bh * S + myrow) * 4);
    float ladd = -log2f(lp[0] + lp[1] + lp[2] + lp[3]);

    f32x4 zero = {0.f, 0.f, 0.f, 0.f};
    f32x4 c[4] = {zero, zero, zero, zero};
    float* wo = wout + (size_t)bh * S * S + (size_t)myrow * S;

    for (int kc = 0; kc < KC; kc++) {
        unsigned long long wb = mrow[kc];
        bf16x8 kf[8], vf[8];
#pragma unroll
        for (int u = 0; u < 8; u++)
            kf[u] = *(const bf16x8*)(kb + ((size_t)kc * 8 + u) * 512 + lane * 8);
#pragma unroll
        for (int u = 0; u < 8; u++)
            vf[u] = *(const bf16x8*)(vb + ((size_t)kc * 8 + u) * 512 + lane * 8);

        f32x4 s[4];
        __builtin_amdgcn_s_setprio(1);
#pragma unroll
        for (int t = 0; t < 4; t++) {
            f32x4 z = {0.f, 0.f, 0.f, 0.f};
            z = MFMA(kf[t * 2], a0, z);       // swapped QK^T: s[t][r] = S[myrow][kc*64+t*16+lg*4+r]
            z = MFMA(kf[t * 2 + 1], a1, z);
            s[t] = z;
        }
        __builtin_amdgcn_s_setprio(0);

        // mask + exp + normalize, direct float4 weight stores (lane owns 16 keys of its row)
        f32x4 wv[4];
#pragma unroll
        for (int t = 0; t < 4; t++) {
#pragma unroll
            for (int j = 0; j < 4; j++) {
                float w = exp2f(__fmaf_rn(s[t][j], LOG2E, ladd));
                if ((wb >> (t * 16 + lg * 4 + j)) & 1ull) w = 0.f;
                wv[t][j] = w;
            }
            *(f32x4*)(wo + kc * 64 + t * 16 + lg * 4) = wv[t];
        }

        // P -> A-fragments: zero shuffles (V rows pi-permuted); pack own registers
        union { __hip_bfloat162 h2[4]; bf16x8 v; } pa0, pa1;
        pa0.h2[0] = __float22bfloat162_rn({wv[0][0], wv[0][1]});
        pa0.h2[1] = __float22bfloat162_rn({wv[0][2], wv[0][3]});
        pa0.h2[2] = __float22bfloat162_rn({wv[1][0], wv[1][1]});
        pa0.h2[3] = __float22bfloat162_rn({wv[1][2], wv[1][3]});
        pa1.h2[0] = __float22bfloat162_rn({wv[2][0], wv[2][1]});
        pa1.h2[1] = __float22bfloat162_rn({wv[2][2], wv[2][3]});
        pa1.h2[2] = __float22bfloat162_rn({wv[3][0], wv[3][1]});
        pa1.h2[3] = __float22bfloat162_rn({wv[3][2], wv[3][3]});

        __builtin_amdgcn_s_setprio(1);
#pragma unroll
        for (int dt = 0; dt < 4; dt++) {
            c[dt] = MFMA(pa0.v, vf[dt * 2], c[dt]);
            c[dt] = MFMA(pa1.v, vf[dt * 2 + 1], c[dt]);
        }
        __builtin_amdgcn_s_setprio(0);
    }

    // ---- ctx -> wave-local LDS in ctxF chunk layout, coalesced flush ----
    unsigned short* cls = (unsigned short*)(smem + wave * 2048);
#pragma unroll
    for (int dt = 0; dt < 4; dt++)
#pragma unroll
        for (int j = 0; j < 4; j++)
            cls[(dt >> 1) * 512 + (((dt & 1) * 2 + (lr >> 3)) * 16 + lg * 4 + j) * 8 + (lr & 7)] =
                f2bf(c[dt][j]);
    int rtc = b * 128 + qc * 4 + wave;
    unsigned short* gp = ctxF + ((size_t)(rtc * 16 + h * 2)) * 512 + lane * 16;
    const uint4* clsv = (const uint4*)cls;
    uint4 u0 = clsv[lane * 2];
    uint4 u1 = clsv[lane * 2 + 1];
    *(uint4*)gp = u0;
    *(uint4*)(gp + 8) = u1;
}

// ---------- output projection: ctxF(frag bf16) x Wofrag -> fp32 out ----------
__global__ __launch_bounds__(256, 3) void k_outproj(const unsigned short* __restrict__ ctxF,
                                                    const unsigned short* __restrict__ wfo,
                                                    float* __restrict__ out) {
    int lin = blockIdx.x;                 // 0..767
    int x = lin & 7, r = lin >> 3;        // r 0..95
    int by = r >> 3, bxg = r & 7;         // by 0..11
    int bx = bxg * 8 + x;

    const int wave = threadIdx.x >> 6, lane = threadIdx.x & 63;
    const int lr = lane & 15, lg = lane >> 4;

    f32x4 zero = {0.f, 0.f, 0.f, 0.f};
    f32x4 acc[4] = {zero, zero, zero, zero};

    const unsigned short* ap = ctxF + ((size_t)(bx * 4 + wave) * 16) * 512 + (size_t)lane * 8;
    bf16x8 a = *(const bf16x8*)ap;
#pragma unroll
    for (int ks = 0; ks < 16; ks++) {
        bf16x8 an;
        if (ks < 15) an = *(const bf16x8*)(ap + (ks + 1) * 512);
#pragma unroll
        for (int nt = 0; nt < 4; nt++) {
            const unsigned short* bp = wfo + ((size_t)(ks * 48 + by * 4 + nt) * 64 + lane) * 8;
            bf16x8 bb = *(const bf16x8*)bp;
            acc[nt] = MFMA(a, bb, acc[nt]);
        }
        a = an;
    }
#pragma unroll
    for (int nt = 0; nt < 4; nt++) {
        int col = by * 64 + nt * 16 + lr;
#pragma unroll
        for (int j = 0; j < 4; j++) {
            int rr = bx * 64 + wave * 16 + lg * 4 + j;
            out[(size_t)rr * DM + col] = acc[nt][j];
        }
    }
}

extern "C" void kernel_launch(void* const* d_in, const int* in_sizes, int n_in,
                              void* d_out, int out_size, void* d_ws, size_t ws_size,
                              hipStream_t stream) {
    const float* q = (const float*)d_in[0];
    const float* k = (const float*)d_in[1];
    const float* v = (const float*)d_in[2];
    const unsigned char* mask = (const unsigned char*)d_in[3];
    const float* Wq = (const float*)d_in[4];
    const float* Wk = (const float*)d_in[5];
    const float* Wv = (const float*)d_in[6];
    const float* Wo = (const float*)d_in[7];

    float* out = (float*)d_out;
    float* weights = out + (size_t)BS * S * DM;
    // Af (18.9 MB) lives at the start of the weights region (dead once k_proj ends;
    // k_attn overwrites it with real weights afterwards).
    unsigned short* Af = (unsigned short*)weights;

    char* ws = (char*)d_ws;
    const size_t WT_SZ = (size_t)393216 * 2;         // 768 KiB each
    const size_t HEAD_SZ = (size_t)BH * S * DK * 2;  // 4 MiB
    unsigned short* Wfq = (unsigned short*)(ws + 0 * WT_SZ);
    unsigned short* Wfk = (unsigned short*)(ws + 1 * WT_SZ);
    unsigned short* Wfv = (unsigned short*)(ws + 2 * WT_SZ);
    unsigned short* Wfo = (unsigned short*)(ws + 3 * WT_SZ);
    char* base = ws + 4 * WT_SZ;
    unsigned short* Qh = (unsigned short*)(base + 0 * HEAD_SZ);
    unsigned short* Kf = (unsigned short*)(base + 1 * HEAD_SZ);
    unsigned short* Vf = (unsigned short*)(base + 2 * HEAD_SZ);
    unsigned short* ctxF = (unsigned short*)(base + 3 * HEAD_SZ);
    unsigned long long* mbits = (unsigned long long*)(base + 4 * HEAD_SZ);
    float* lpart = (float*)(base + 4 * HEAD_SZ + 1048576);   // [BH][S][4] f32 = 512 KiB
    if (ws_size < 4 * WT_SZ + 4 * HEAD_SZ + 1048576 + (size_t)BH * S * 4 * 4) return;

    k_prep<<<10880, 256, 0, stream>>>(q, k, v, mask, Wq, Wk, Wv, Wo, Af, mbits,
                                      Wfq, Wfk, Wfv, Wfo);
    k_proj<<<768, 256, 0, stream>>>(Af, Wfq, Wfk, Wfv, Qh, Kf, Vf);
    k_lsum<<<2048, 256, 0, stream>>>(Qh, Kf, mbits, lpart);
    k_attn<<<512, 256, 0, stream>>>(Qh, Kf, Vf, mbits, lpart, weights, ctxF);
    k_outproj<<<768, 256, 0, stream>>>(ctxF, Wfo, out);
}

// Round 11
// 170.996 us; speedup vs baseline: 1.3786x; 1.0213x over previous
//
#include <hip/hip_runtime.h>
#include <hip/hip_bf16.h>

#define DEV __device__ __forceinline__

typedef __attribute__((ext_vector_type(8))) short bf16x8;
typedef __attribute__((ext_vector_type(4))) float f32x4;

#define MFMA(a, b, c) __builtin_amdgcn_mfma_f32_16x16x32_bf16(a, b, c, 0, 0, 0)

// sizes (fixed problem)
#define BS 2
#define S 2048
#define DM 768
#define NH 8
#define DK 64
#define NPROJ 512   // NH*DK
#define BH 16       // BS*NH
#define KC 32       // S/64
#define LOG2E 1.44269504089f

DEV unsigned short f2bf(float f) {
    unsigned int u = __float_as_uint(f);
    unsigned int r = u + 0x7fffu + ((u >> 16) & 1u);
    return (unsigned short)(r >> 16);
}

// ---------- fused prep: acast (blk<9216) | mask bits (<9728) | wfrag (<10880) ----------
__global__ __launch_bounds__(256) void k_prep(
    const float* __restrict__ q, const float* __restrict__ k, const float* __restrict__ v,
    const unsigned char* __restrict__ mask,
    const float* __restrict__ Wq, const float* __restrict__ Wk, const float* __restrict__ Wv,
    const float* __restrict__ Wo,
    unsigned short* __restrict__ Af, unsigned long long* __restrict__ bits,
    unsigned short* __restrict__ Oq, unsigned short* __restrict__ Ok,
    unsigned short* __restrict__ Ov, unsigned short* __restrict__ Oo) {
    int blk = blockIdx.x;
    if (blk < 9216) {
        // q,k,v fp32 -> bf16 MFMA-A-fragment order
        int p = blk / 3072;
        int f = (blk % 3072) * 256 + threadIdx.x;
        const float* A = (p == 0) ? q : ((p == 1) ? k : v);
        float4 x = *(const float4*)(A + (size_t)f * 4);
        int col4 = f % 192, row = f / 192;
        int c0 = col4 * 4;
        int ks = c0 >> 5, lgp = (c0 & 31) >> 3, e0 = c0 & 7;
        int rt = p * 256 + (row >> 4);
        size_t dst = ((size_t)(rt * 24 + ks) * 64 + lgp * 16 + (row & 15)) * 8 + e0;
        ushort4 o;
        o.x = f2bf(x.x); o.y = f2bf(x.y); o.z = f2bf(x.z); o.w = f2bf(x.w);
        *(ushort4*)(Af + dst) = o;
    } else if (blk < 9728) {
        // mask bytes -> bitmask
        int w = (blk - 9216) * 256 + threadIdx.x;
        const unsigned long long* m8 = (const unsigned long long*)(mask + (size_t)w * 64);
        unsigned long long out = 0ull;
#pragma unroll
        for (int i = 0; i < 8; i++) {
            unsigned long long xv = m8[i];
#pragma unroll
            for (int kk = 0; kk < 8; kk++)
                if ((xv >> (8 * kk)) & 0xffull) out |= 1ull << (i * 8 + kk);
        }
        bits[w] = out;
    } else {
        // W -> MFMA-B-fragment order
        int i = blk - 9728;                  // 0..1151
        int ks = i % 24, byy = (i / 24) % 12, z = i / 288;
        const float* W = (z == 0) ? Wq : ((z == 1) ? Wk : ((z == 2) ? Wv : Wo));
        unsigned short* out = (z == 0) ? Oq : ((z == 1) ? Ok : ((z == 2) ? Ov : Oo));
        int N = (z == 3) ? DM : NPROJ;
        float scale = (z == 0) ? 0.125f : 1.0f;
        int wave = threadIdx.x >> 6, lane = threadIdx.x & 63;
        int nc = byy * 4 + wave;
        if (z < 3) { if (ks >= 24 || nc >= 32) return; }
        else       { if (ks >= 16) return; }
        int lr = lane & 15, lg = lane >> 4;
        int NC = N >> 4;
        const float* src = W + (size_t)(ks * 32 + lg * 8) * N + nc * 16 + lr;
        bf16x8 vv;
#pragma unroll
        for (int e = 0; e < 8; e++) vv[e] = (short)f2bf(src[(size_t)e * N] * scale);
        *(bf16x8*)(out + ((size_t)(ks * NC + nc) * 64 + lane) * 8) = vv;
    }
}

// ---------- projection GEMM: Af(frag) x Wfrag -> Qh/Kf/Vf via LDS repack + coalesced flush ----------
// Vf key-rows are stored pre-permuted by pi(h*32+lg*8+e) = h*32+(e>>2)*16+lg*4+(e&3)
// so k_attn's P fragments need no cross-lane movement.
__global__ __launch_bounds__(256, 3) void k_proj(
    const unsigned short* __restrict__ Af,
    const unsigned short* __restrict__ Wfq, const unsigned short* __restrict__ Wfk,
    const unsigned short* __restrict__ Wfv,
    unsigned short* __restrict__ Qh, unsigned short* __restrict__ Kf,
    unsigned short* __restrict__ Vf) {
    __shared__ __align__(16) unsigned short ls[4096];  // 8 KB repack buffer
    // XCD-aware decode: all 4 by-blocks of one (p,bx) land on the same XCD
    int lin = blockIdx.x;                    // 0..767
    int x = lin & 7, r = lin >> 3;           // r 0..95
    int by = r & 3;
    int pbx = (r >> 2) * 8 + x;              // 0..191
    int p = pbx >> 6, bx = pbx & 63;

    const unsigned short* wf = (p == 0) ? Wfq : ((p == 1) ? Wfk : Wfv);

    const int wave = threadIdx.x >> 6, lane = threadIdx.x & 63;
    const int lr = lane & 15, lg = lane >> 4;

    f32x4 zero = {0.f, 0.f, 0.f, 0.f};
    f32x4 acc[8] = {zero, zero, zero, zero, zero, zero, zero, zero};

    const unsigned short* afb =
        Af + ((size_t)(p * 256 + bx * 4 + wave) * 24) * 512 + (size_t)lane * 8;
    bf16x8 a = *(const bf16x8*)afb;
#pragma unroll
    for (int ks = 0; ks < 24; ks++) {
        bf16x8 an;
        if (ks < 23) an = *(const bf16x8*)(afb + (ks + 1) * 512);
        const unsigned short* wp = wf + ((size_t)(ks * 32 + by * 8) * 64 + lane) * 8;
#pragma unroll
        for (int nt = 0; nt < 8; nt++) {
            bf16x8 b = *(const bf16x8*)(wp + (size_t)nt * 512);
            acc[nt] = MFMA(a, b, acc[nt]);
        }
        a = an;
    }

    const int bb = bx >> 5, kq = bx & 31;  // batch, kc (or 64-row group for Q)
#pragma unroll
    for (int half = 0; half < 2; half++) {
        if (half) __syncthreads();   // previous flush reads done before overwrite
        int h = by * 2 + half;
        int bh = bb * NH + h;
        // ---- write phase: acc -> LDS in exact global-chunk layout ----
#pragma unroll
        for (int nt4 = 0; nt4 < 4; nt4++) {
            int nt = half * 4 + nt4;
#pragma unroll
            for (int j = 0; j < 4; j++) {
                unsigned short val = f2bf(acc[nt][j]);
                int lsaddr;
                if (p == 0) {
                    lsaddr = (wave * 16 + lg * 4 + j) * 64 + nt4 * 16 + lr;
                } else if (p == 1) {
                    int hh = nt4 >> 1;
                    int lgk = ((nt4 & 1) << 1) | (lr >> 3);
                    lsaddr = (wave * 2 + hh) * 512 + (lgk * 16 + lg * 4 + j) * 8 + (lr & 7);
                } else {
                    // V with pi-permuted key rows: klo = wave*16+lg*4+j
                    lsaddr = (nt4 * 2 + (wave >> 1)) * 512 + (lg * 16 + lr) * 8 + (wave & 1) * 4 + j;
                }
                ls[lsaddr] = val;
            }
        }
        __syncthreads();
        // ---- flush: 8 KB coalesced ----
        unsigned short* gp;
        if (p == 0)      gp = Qh + ((size_t)bh * S + kq * 64) * DK;
        else if (p == 1) gp = Kf + ((size_t)bh * KC + kq) * 4096;
        else             gp = Vf + ((size_t)bh * KC + kq) * 4096;
        const uint4* lsv = (const uint4*)ls;
        uint4 v0 = lsv[threadIdx.x * 2];
        uint4 v1 = lsv[threadIdx.x * 2 + 1];
        *(uint4*)(gp + threadIdx.x * 16) = v0;
        *(uint4*)(gp + threadIdx.x * 16 + 8) = v1;
    }
}

// ---------- softmax denominators (swapped QK^T: lane-local rows), K-split x4, K-prefetch ----------
__global__ __launch_bounds__(256, 4) void k_lsum(
    const unsigned short* __restrict__ Qh, const unsigned short* __restrict__ Kf,
    const unsigned long long* __restrict__ mbits, float* __restrict__ lpart) {
    int lin = blockIdx.x;
    int x = lin & 7, i = lin >> 3;          // i 0..255
    int bh = (x << 1) | (i >> 7);
    int i7 = i & 127;
    int qc = i7 >> 2, ks = i7 & 3;
    int b = bh >> 3;
    const int wave = threadIdx.x >> 6, lane = threadIdx.x & 63;
    const int lr = lane & 15, lg = lane >> 4;
    const int myrow = qc * 64 + wave * 16 + lr;

    const unsigned short* qp = Qh + ((size_t)bh * S + myrow) * DK + lg * 8;
    bf16x8 a0 = *(const bf16x8*)qp;
    bf16x8 a1 = *(const bf16x8*)(qp + 32);

    const unsigned short* kb = Kf + (size_t)bh * KC * 4096;
    const unsigned long long* mrow = mbits + (size_t)b * S * KC + (size_t)myrow * KC;

    const int kc0 = ks * 8;
    bf16x8 kf[8];
    unsigned long long wb = mrow[kc0];
#pragma unroll
    for (int u = 0; u < 8; u++)
        kf[u] = *(const bf16x8*)(kb + ((size_t)kc0 * 8 + u) * 512 + lane * 8);

    float lsum = 0.f;
    for (int kk = 0; kk < 8; kk++) {
        int kc = kc0 + kk;
        int nkc = (kk < 7) ? kc + 1 : kc;
        bf16x8 kn[8];
        unsigned long long wbn = mrow[nkc];
#pragma unroll
        for (int u = 0; u < 8; u++)
            kn[u] = *(const bf16x8*)(kb + ((size_t)nkc * 8 + u) * 512 + lane * 8);
        f32x4 s[4];
#pragma unroll
        for (int t = 0; t < 4; t++) {
            f32x4 z = {0.f, 0.f, 0.f, 0.f};
            z = MFMA(kf[t * 2], a0, z);       // swapped: rows=keys, cols=q
            z = MFMA(kf[t * 2 + 1], a1, z);
            s[t] = z;
        }
#pragma unroll
        for (int t = 0; t < 4; t++)
#pragma unroll
            for (int j = 0; j < 4; j++) {
                float p = exp2f(s[t][j] * LOG2E);
                if ((wb >> (t * 16 + lg * 4 + j)) & 1ull) p = 0.f;
                lsum += p;
            }
#pragma unroll
        for (int u = 0; u < 8; u++) kf[u] = kn[u];
        wb = wbn;
    }
    lsum += __shfl_xor(lsum, 16);
    lsum += __shfl_xor(lsum, 32);
    if (lg == 0) lpart[((size_t)bh * S + myrow) * 4 + ks] = lsum;
}

// ---------- single-pass attention, swapped scores, K-prefetch double-buffer ----------
__global__ __launch_bounds__(256, 2) void k_attn(
    const unsigned short* __restrict__ Qh, const unsigned short* __restrict__ Kf,
    const unsigned short* __restrict__ Vf, const unsigned long long* __restrict__ mbits,
    const float* __restrict__ lpart, float* __restrict__ wout,
    unsigned short* __restrict__ ctxF) {
    __shared__ __align__(16) char smem[4 * 2048];  // per-wave ctx repack only
    int lin = blockIdx.x;                 // 0..511
    int x = lin & 7, i = lin >> 3;        // i 0..63
    int bh = (x << 1) | (i >> 5), qc = i & 31;
    int b = bh >> 3, h = bh & 7;
    const int wave = threadIdx.x >> 6, lane = threadIdx.x & 63;
    const int lr = lane & 15, lg = lane >> 4;
    const int myrow = qc * 64 + wave * 16 + lr;

    const unsigned short* qp = Qh + ((size_t)bh * S + myrow) * DK + lg * 8;
    bf16x8 a0 = *(const bf16x8*)qp;
    bf16x8 a1 = *(const bf16x8*)(qp + 32);

    const unsigned short* kb = Kf + (size_t)bh * KC * 4096;
    const unsigned short* vb = Vf + (size_t)bh * KC * 4096;
    const unsigned long long* mrow = mbits + (size_t)b * S * KC + (size_t)myrow * KC;

    // fold 1/l into the exponent: w = exp2(s*log2e - log2(l))
    f32x4 lp = *(const f32x4*)(lpart + ((size_t)bh * S + myrow) * 4);
    float ladd = -log2f(lp[0] + lp[1] + lp[2] + lp[3]);

    f32x4 zero = {0.f, 0.f, 0.f, 0.f};
    f32x4 c[4] = {zero, zero, zero, zero};
    float* wo = wout + (size_t)bh * S * S + (size_t)myrow * S;

    bf16x8 kf[8];
    unsigned long long wb = mrow[0];
#pragma unroll
    for (int u = 0; u < 8; u++)
        kf[u] = *(const bf16x8*)(kb + (size_t)u * 512 + lane * 8);

    for (int kc = 0; kc < KC; kc++) {
        int nkc = (kc + 1 < KC) ? kc + 1 : kc;
        bf16x8 kn[8], vf[8];
        unsigned long long wbn = mrow[nkc];
#pragma unroll
        for (int u = 0; u < 8; u++)
            kn[u] = *(const bf16x8*)(kb + ((size_t)nkc * 8 + u) * 512 + lane * 8);
#pragma unroll
        for (int u = 0; u < 8; u++)
            vf[u] = *(const bf16x8*)(vb + ((size_t)kc * 8 + u) * 512 + lane * 8);

        f32x4 s[4];
        __builtin_amdgcn_s_setprio(1);
#pragma unroll
        for (int t = 0; t < 4; t++) {
            f32x4 z = {0.f, 0.f, 0.f, 0.f};
            z = MFMA(kf[t * 2], a0, z);       // swapped QK^T: s[t][r] = S[myrow][kc*64+t*16+lg*4+r]
            z = MFMA(kf[t * 2 + 1], a1, z);
            s[t] = z;
        }
        __builtin_amdgcn_s_setprio(0);

        // mask + exp + normalize, direct float4 weight stores (lane owns 16 keys of its row)
        f32x4 wv[4];
#pragma unroll
        for (int t = 0; t < 4; t++) {
#pragma unroll
            for (int j = 0; j < 4; j++) {
                float w = exp2f(__fmaf_rn(s[t][j], LOG2E, ladd));
                if ((wb >> (t * 16 + lg * 4 + j)) & 1ull) w = 0.f;
                wv[t][j] = w;
            }
            *(f32x4*)(wo + kc * 64 + t * 16 + lg * 4) = wv[t];
        }

        // P -> A-fragments: zero shuffles (V rows pi-permuted); pack own registers
        union { __hip_bfloat162 h2[4]; bf16x8 v8; } pa0, pa1;
        pa0.h2[0] = __float22bfloat162_rn({wv[0][0], wv[0][1]});
        pa0.h2[1] = __float22bfloat162_rn({wv[0][2], wv[0][3]});
        pa0.h2[2] = __float22bfloat162_rn({wv[1][0], wv[1][1]});
        pa0.h2[3] = __float22bfloat162_rn({wv[1][2], wv[1][3]});
        pa1.h2[0] = __float22bfloat162_rn({wv[2][0], wv[2][1]});
        pa1.h2[1] = __float22bfloat162_rn({wv[2][2], wv[2][3]});
        pa1.h2[2] = __float22bfloat162_rn({wv[3][0], wv[3][1]});
        pa1.h2[3] = __float22bfloat162_rn({wv[3][2], wv[3][3]});

        __builtin_amdgcn_s_setprio(1);
#pragma unroll
        for (int dt = 0; dt < 4; dt++) {
            c[dt] = MFMA(pa0.v8, vf[dt * 2], c[dt]);
            c[dt] = MFMA(pa1.v8, vf[dt * 2 + 1], c[dt]);
        }
        __builtin_amdgcn_s_setprio(0);

#pragma unroll
        for (int u = 0; u < 8; u++) kf[u] = kn[u];
        wb = wbn;
    }

    // ---- ctx -> wave-local LDS in ctxF chunk layout, coalesced flush ----
    unsigned short* cls = (unsigned short*)(smem + wave * 2048);
#pragma unroll
    for (int dt = 0; dt < 4; dt++)
#pragma unroll
        for (int j = 0; j < 4; j++)
            cls[(dt >> 1) * 512 + (((dt & 1) * 2 + (lr >> 3)) * 16 + lg * 4 + j) * 8 + (lr & 7)] =
                f2bf(c[dt][j]);
    int rtc = b * 128 + qc * 4 + wave;
    unsigned short* gp = ctxF + ((size_t)(rtc * 16 + h * 2)) * 512 + lane * 16;
    const uint4* clsv = (const uint4*)cls;
    uint4 u0 = clsv[lane * 2];
    uint4 u1 = clsv[lane * 2 + 1];
    *(uint4*)gp = u0;
    *(uint4*)(gp + 8) = u1;
}

// ---------- output projection: ctxF(frag bf16) x Wofrag -> fp32 out ----------
__global__ __launch_bounds__(256, 3) void k_outproj(const unsigned short* __restrict__ ctxF,
                                                    const unsigned short* __restrict__ wfo,
                                                    float* __restrict__ out) {
    int lin = blockIdx.x;                 // 0..767
    int x = lin & 7, r = lin >> 3;        // r 0..95
    int by = r >> 3, bxg = r & 7;         // by 0..11
    int bx = bxg * 8 + x;

    const int wave = threadIdx.x >> 6, lane = threadIdx.x & 63;
    const int lr = lane & 15, lg = lane >> 4;

    f32x4 zero = {0.f, 0.f, 0.f, 0.f};
    f32x4 acc[4] = {zero, zero, zero, zero};

    const unsigned short* ap = ctxF + ((size_t)(bx * 4 + wave) * 16) * 512 + (size_t)lane * 8;
    bf16x8 a = *(const bf16x8*)ap;
#pragma unroll
    for (int ks = 0; ks < 16; ks++) {
        bf16x8 an;
        if (ks < 15) an = *(const bf16x8*)(ap + (ks + 1) * 512);
#pragma unroll
        for (int nt = 0; nt < 4; nt++) {
            const unsigned short* bp = wfo + ((size_t)(ks * 48 + by * 4 + nt) * 64 + lane) * 8;
            bf16x8 bb = *(const bf16x8*)bp;
            acc[nt] = MFMA(a, bb, acc[nt]);
        }
        a = an;
    }
#pragma unroll
    for (int nt = 0; nt < 4; nt++) {
        int col = by * 64 + nt * 16 + lr;
#pragma unroll
        for (int j = 0; j < 4; j++) {
            int rr = bx * 64 + wave * 16 + lg * 4 + j;
            out[(size_t)rr * DM + col] = acc[nt][j];
        }
    }
}

extern "C" void kernel_launch(void* const* d_in, const int* in_sizes, int n_in,
                              void* d_out, int out_size, void* d_ws, size_t ws_size,
                              hipStream_t stream) {
    const float* q = (const float*)d_in[0];
    const float* k = (const float*)d_in[1];
    const float* v = (const float*)d_in[2];
    const unsigned char* mask = (const unsigned char*)d_in[3];
    const float* Wq = (const float*)d_in[4];
    const float* Wk = (const float*)d_in[5];
    const float* Wv = (const float*)d_in[6];
    const float* Wo = (const float*)d_in[7];

    float* out = (float*)d_out;
    float* weights = out + (size_t)BS * S * DM;
    // Af (18.9 MB) lives at the start of the weights region (dead once k_proj ends;
    // k_attn overwrites it with real weights afterwards).
    unsigned short* Af = (unsigned short*)weights;

    char* ws = (char*)d_ws;
    const size_t WT_SZ = (size_t)393216 * 2;         // 768 KiB each
    const size_t HEAD_SZ = (size_t)BH * S * DK * 2;  // 4 MiB
    unsigned short* Wfq = (unsigned short*)(ws + 0 * WT_SZ);
    unsigned short* Wfk = (unsigned short*)(ws + 1 * WT_SZ);
    unsigned short* Wfv = (unsigned short*)(ws + 2 * WT_SZ);
    unsigned short* Wfo = (unsigned short*)(ws + 3 * WT_SZ);
    char* base = ws + 4 * WT_SZ;
    unsigned short* Qh = (unsigned short*)(base + 0 * HEAD_SZ);
    unsigned short* Kf = (unsigned short*)(base + 1 * HEAD_SZ);
    unsigned short* Vf = (unsigned short*)(base + 2 * HEAD_SZ);
    unsigned short* ctxF = (unsigned short*)(base + 3 * HEAD_SZ);
    unsigned long long* mbits = (unsigned long long*)(base + 4 * HEAD_SZ);
    float* lpart = (float*)(base + 4 * HEAD_SZ + 1048576);   // [BH][S][4] f32 = 512 KiB
    if (ws_size < 4 * WT_SZ + 4 * HEAD_SZ + 1048576 + (size_t)BH * S * 4 * 4) return;

    k_prep<<<10880, 256, 0, stream>>>(q, k, v, mask, Wq, Wk, Wv, Wo, Af, mbits,
                                      Wfq, Wfk, Wfv, Wfo);
    k_proj<<<768, 256, 0, stream>>>(Af, Wfq, Wfk, Wfv, Qh, Kf, Vf);
    k_lsum<<<2048, 256, 0, stream>>>(Qh, Kf, mbits, lpart);
    k_attn<<<512, 256, 0, stream>>>(Qh, Kf, Vf, mbits, lpart, weights, ctxF);
    k_outproj<<<768, 256, 0, stream>>>(ctxF, Wfo, out);
}